// Round 1
// 20899.313 us; speedup vs baseline: 1.7407x; 1.7407x over previous
//
#include <hip/hip_runtime.h>
#include <cstdint>

// Decoder: S=128, B=32, H=E=512, L=2, V=32000, heads=8, dk=64, T=128 steps.
// Round 2: latency attack. All per-step GEMMs K-split across blocks for full-chip
// wave coverage + ring-prefetched inner loops; Wo folded into W_out (Weff) offline;
// attention split into 256 independent (b,h) single-wave blocks.
//  per step: gates(l0) -> act(l0) -> gates(l1) -> act(l1) -> attn -> logits(x4 kb) -> final

#define B_ 32
#define H_ 512
#define V_ 32000
#define S_ 128
#define NH_ 8
#define DK_ 64

// ---- workspace float offsets ----
// NOTE: order matters: several kernels ring-prefetch past their buffer end; each
// over-readable buffer is followed by >=1MB of other allocations.
static const size_t o_WeffT = 0;                                   // [512][32000] (+4-row over-read -> Wcat)
static const size_t o_Wcat  = o_WeffT + (size_t)512 * 32000;       // [2][1024][2048] (+~56KB over-read -> Wqt)
static const size_t o_Wqt   = o_Wcat  + (size_t)2 * 1024 * 2048;   // [512][512] (+16KB over-read -> WkvT)
static const size_t o_WkvT  = o_Wqt   + (size_t)512 * 512;         // [512][1024] (Wk|Wv)
static const size_t o_kT    = o_WkvT  + (size_t)512 * 1024;        // [32][8][64][128]
static const size_t o_vT    = o_kT    + (size_t)B_ * NH_ * DK_ * S_;   // [32][8][128][64]
static const size_t o_h     = o_vT    + (size_t)B_ * NH_ * S_ * DK_;   // [2pp][2l][32][512]
static const size_t o_c     = o_h     + (size_t)2 * 2 * B_ * H_;
static const size_t o_attnT = o_c     + (size_t)2 * 2 * B_ * H_;   // [512][32] raw attn (pre-Wo)
static const size_t o_gpart = o_attnT + (size_t)H_ * B_;           // [4][32][2048] gate partials
static const size_t o_part  = o_gpart + (size_t)4 * B_ * 2048;     // [4][32][32000] logit partials
static const size_t o_beff  = o_part  + (size_t)4 * B_ * V_;       // [32000]
static const size_t o_keys  = o_beff  + (size_t)V_;                // u64[125][32]

// ---------------- prep kernels ----------------

// in[M][K] row-major -> out[k*ldout + m]
__global__ void transpose_k(const float* __restrict__ in, float* __restrict__ out,
                            int M, int K, int ldout) {
    __shared__ float tile[32][33];
    int m0 = blockIdx.x * 32, k0 = blockIdx.y * 32;
    int tx = threadIdx.x & 31, ty = threadIdx.x >> 5;  // ty: 0..7
    #pragma unroll
    for (int r = 0; r < 32; r += 8) {
        int m = m0 + ty + r, k = k0 + tx;
        tile[ty + r][tx] = in[(size_t)m * K + k];
    }
    __syncthreads();
    #pragma unroll
    for (int r = 0; r < 32; r += 8) {
        int k = k0 + ty + r, m = m0 + tx;
        out[(size_t)k * ldout + m] = tile[tx][ty + r];
    }
}

// Build Wcat[l][k][n], n = j*4+g, k<512 from W_ih[l][g*512+j][k], else W_hh.
__global__ void lstm_prep(const float* __restrict__ Wih, const float* __restrict__ Whh,
                          float* __restrict__ Wcat) {
    int l = blockIdx.z, jt = blockIdx.x, kt = blockIdx.y;
    __shared__ float tl[4][32][33];
    int tid = threadIdx.x;
    #pragma unroll
    for (int rep = 0; rep < 16; ++rep) {
        int idx = rep * 256 + tid;
        int rl = idx >> 5, kk = idx & 31;
        int g = rl >> 5, j = rl & 31;
        int k = kt * 32 + kk;
        int row = g * 512 + jt * 32 + j;
        const float* src = (k < 512)
            ? (Wih + (size_t)l * 2048 * 512 + (size_t)row * 512 + k)
            : (Whh + (size_t)l * 2048 * 512 + (size_t)row * 512 + (k - 512));
        tl[g][j][kk] = *src;
    }
    __syncthreads();
    #pragma unroll
    for (int rep = 0; rep < 16; ++rep) {
        int idx = rep * 256 + tid;
        int kk = idx >> 7, nn = idx & 127;
        int j = nn >> 2, g = nn & 3;
        Wcat[(size_t)l * 1024 * 2048 + (size_t)(kt * 32 + kk) * 2048 + jt * 128 + nn] =
            tl[g][j][kk];
    }
}

// zero out[:,0,:]
__global__ void zero_kernel(float* __restrict__ out) {
    size_t idx = (size_t)blockIdx.x * 256 + threadIdx.x;
    size_t total = (size_t)B_ * V_;
    for (size_t i = idx; i < total; i += (size_t)gridDim.x * 256) {
        size_t b = i / V_, v = i % V_;
        out[b * 128 * V_ + v] = 0.f;
    }
}

// k/v precompute: per (s=g, n in [0,1024)): dot over K=512 of hs rows, write permuted.
__global__ __launch_bounds__(256) void kv_kernel(
    const float* __restrict__ hs, const float* __restrict__ WkvT,
    const float* __restrict__ bk, const float* __restrict__ bv,
    float* __restrict__ kT, float* __restrict__ vT) {
    int n = blockIdx.x * 256 + threadIdx.x;  // 0..1023
    int g = blockIdx.y;                      // s: 0..127
    float bias = (n < 512) ? bk[n] : bv[n - 512];
    float acc[32];
    #pragma unroll
    for (int b = 0; b < 32; ++b) acc[b] = bias;
    const float* xbase = hs + (size_t)g * 32 * 512;
    for (int k = 0; k < 512; k += 4) {
        float w0 = WkvT[(size_t)(k + 0) * 1024 + n];
        float w1 = WkvT[(size_t)(k + 1) * 1024 + n];
        float w2 = WkvT[(size_t)(k + 2) * 1024 + n];
        float w3 = WkvT[(size_t)(k + 3) * 1024 + n];
        #pragma unroll
        for (int b = 0; b < 32; ++b) {
            const float* xr = xbase + (size_t)b * 512 + k;  // uniform -> s_load
            acc[b] += xr[0] * w0 + xr[1] * w1 + xr[2] * w2 + xr[3] * w3;
        }
    }
    if (n < 512) {
        int h = n >> 6, d = n & 63;
        #pragma unroll
        for (int b = 0; b < 32; ++b)
            kT[(((size_t)b * NH_ + h) * DK_ + d) * S_ + g] = acc[b];
    } else {
        int n2 = n - 512;
        int h = n2 >> 6, d = n2 & 63;
        #pragma unroll
        for (int b = 0; b < 32; ++b)
            vT[(((size_t)b * NH_ + h) * S_ + n2 / 64 * 0 + g) * DK_ + d] = acc[b];
    }
}

// WeffT[h][v] = sum_n WoutT?  -- computed from W_out directly via LDS tiles:
// WeffT[h][v] = sum_n W_out[v][n] * Wo[n][h];  beff[v] = b_out[v] + sum_n W_out[v][n]*bo[n]
__global__ __launch_bounds__(256) void weff_kernel(
    const float* __restrict__ Wout, const float* __restrict__ Wo,
    const float* __restrict__ bo, const float* __restrict__ b_out,
    float* __restrict__ WeffT, float* __restrict__ beff) {
    const int tid = threadIdx.x;
    const int v = blockIdx.x * 256 + tid;     // 0..31999
    const int h0 = blockIdx.y * 32;           // 16 h-blocks
    const bool hb0 = (blockIdx.y == 0);
    __shared__ float tl[32][257];             // [n-in-tile][v-in-block], padded
    float acc[32];
    #pragma unroll
    for (int i = 0; i < 32; ++i) acc[i] = 0.f;
    float accb = 0.f;
    const int v0 = blockIdx.x * 256;
    for (int nt = 0; nt < 16; ++nt) {
        __syncthreads();
        #pragma unroll
        for (int rep = 0; rep < 32; ++rep) {
            int vr = rep * 8 + (tid >> 5);
            int nn = tid & 31;
            tl[nn][vr] = Wout[(size_t)(v0 + vr) * 512 + nt * 32 + nn];
        }
        __syncthreads();
        for (int nn = 0; nn < 32; ++nn) {
            float w = tl[nn][tid];
            int n = nt * 32 + nn;
            const float* wo = Wo + (size_t)n * 512 + h0;  // uniform -> s_load
            #pragma unroll
            for (int hh = 0; hh < 32; ++hh) acc[hh] += w * wo[hh];
            if (hb0) accb += w * bo[n];
        }
    }
    #pragma unroll
    for (int hh = 0; hh < 32; ++hh)
        WeffT[(size_t)(h0 + hh) * V_ + v] = acc[hh];
    if (hb0) beff[v] = accb + b_out[v];
}

// ---------------- per-step kernels ----------------

// LSTM gate partials. grid (8 nblk, 8 mblk, 4 kblk) x 256 thr.
// kb=0,1: x-part (cols kb*256..), kb=2,3: h-part. Bias folded into kb==0.
__global__ __launch_bounds__(256) void gates_kernel(
    int l, int t,
    const float* __restrict__ emb, const float* __restrict__ Wcat,
    const float* __restrict__ b_ih, const float* __restrict__ b_hh,
    const unsigned long long* __restrict__ bkeys,
    const float* __restrict__ hbuf, float* __restrict__ gpart) {
    const int rb = (t - 1) & 1, wb = t & 1;
    const int n = blockIdx.x * 256 + threadIdx.x;  // gate col 0..2047
    const int mb = blockIdx.y * 4;
    const int kb = blockIdx.z;                     // 0..3
    const int j = n >> 2, g = n & 3;
    float acc0, acc1, acc2, acc3;
    if (kb == 0) {
        float bias = b_ih[l * 2048 + g * 512 + j] + b_hh[l * 2048 + g * 512 + j];
        acc0 = acc1 = acc2 = acc3 = bias;
    } else {
        acc0 = acc1 = acc2 = acc3 = 0.f;
    }

    const float* row0; const float* row1; const float* row2; const float* row3;
    if (kb < 2) {
        const int off = kb * 256;
        if (l == 0) {
            const float* rr[4];
            #pragma unroll
            for (int i = 0; i < 4; ++i) {
                int m = mb + i;
                int tok = 0;  // SOS
                if (t > 1) {
                    unsigned long long best = 0ull;
                    for (int q = 0; q < 125; ++q) {
                        unsigned long long kk = bkeys[q * 32 + m];
                        best = kk > best ? kk : best;
                    }
                    tok = (int)(0xFFFFFFFFu - (unsigned)(best & 0xFFFFFFFFull));
                }
                rr[i] = emb + (size_t)tok * 512 + off;
            }
            row0 = rr[0]; row1 = rr[1]; row2 = rr[2]; row3 = rr[3];
        } else {
            const float* base = hbuf + ((size_t)wb * 2 + 0) * B_ * H_ + off;  // new h0
            row0 = base + (size_t)(mb + 0) * 512;
            row1 = base + (size_t)(mb + 1) * 512;
            row2 = base + (size_t)(mb + 2) * 512;
            row3 = base + (size_t)(mb + 3) * 512;
        }
    } else {
        const int off = (kb - 2) * 256;
        const float* base = hbuf + ((size_t)rb * 2 + l) * B_ * H_ + off;      // old h_l
        row0 = base + (size_t)(mb + 0) * 512;
        row1 = base + (size_t)(mb + 1) * 512;
        row2 = base + (size_t)(mb + 2) * 512;
        row3 = base + (size_t)(mb + 3) * 512;
    }

    const float* Wp = Wcat + (size_t)l * 1024 * 2048 + (size_t)kb * 256 * 2048 + n;
    float c0 = Wp[(size_t)0 * 2048], c1 = Wp[(size_t)1 * 2048];
    float c2 = Wp[(size_t)2 * 2048], c3 = Wp[(size_t)3 * 2048];
    float c4 = Wp[(size_t)4 * 2048], c5 = Wp[(size_t)5 * 2048];
    float c6 = Wp[(size_t)6 * 2048], c7 = Wp[(size_t)7 * 2048];
    for (int kk = 0; kk < 256; kk += 8) {
        // prefetch next 8 rows (last iter over-reads <=56KB past Wcat -> Wqt region, discarded)
        float t0 = Wp[(size_t)(kk +  8) * 2048], t1 = Wp[(size_t)(kk +  9) * 2048];
        float t2 = Wp[(size_t)(kk + 10) * 2048], t3 = Wp[(size_t)(kk + 11) * 2048];
        float t4 = Wp[(size_t)(kk + 12) * 2048], t5 = Wp[(size_t)(kk + 13) * 2048];
        float t6 = Wp[(size_t)(kk + 14) * 2048], t7 = Wp[(size_t)(kk + 15) * 2048];
        acc0 += row0[kk+0]*c0; acc1 += row1[kk+0]*c0; acc2 += row2[kk+0]*c0; acc3 += row3[kk+0]*c0;
        acc0 += row0[kk+1]*c1; acc1 += row1[kk+1]*c1; acc2 += row2[kk+1]*c1; acc3 += row3[kk+1]*c1;
        acc0 += row0[kk+2]*c2; acc1 += row1[kk+2]*c2; acc2 += row2[kk+2]*c2; acc3 += row3[kk+2]*c2;
        acc0 += row0[kk+3]*c3; acc1 += row1[kk+3]*c3; acc2 += row2[kk+3]*c3; acc3 += row3[kk+3]*c3;
        acc0 += row0[kk+4]*c4; acc1 += row1[kk+4]*c4; acc2 += row2[kk+4]*c4; acc3 += row3[kk+4]*c4;
        acc0 += row0[kk+5]*c5; acc1 += row1[kk+5]*c5; acc2 += row2[kk+5]*c5; acc3 += row3[kk+5]*c5;
        acc0 += row0[kk+6]*c6; acc1 += row1[kk+6]*c6; acc2 += row2[kk+6]*c6; acc3 += row3[kk+6]*c6;
        acc0 += row0[kk+7]*c7; acc1 += row1[kk+7]*c7; acc2 += row2[kk+7]*c7; acc3 += row3[kk+7]*c7;
        c0 = t0; c1 = t1; c2 = t2; c3 = t3; c4 = t4; c5 = t5; c6 = t6; c7 = t7;
    }
    size_t o = ((size_t)kb * 32 + mb) * 2048 + n;
    gpart[o]            = acc0;
    gpart[o + 2048]     = acc1;
    gpart[o + 2 * 2048] = acc2;
    gpart[o + 3 * 2048] = acc3;
}

// Reduce 4 gate partials + activation. grid 64 x 256 (thread per (m,j)).
__global__ __launch_bounds__(256) void act_kernel(
    int l, int t, const float* __restrict__ gpart,
    float* __restrict__ hbuf, float* __restrict__ cbuf) {
    const int rb = (t - 1) & 1, wb = t & 1;
    int idx = blockIdx.x * 256 + threadIdx.x;  // 0..16383
    int m = idx >> 9, j = idx & 511;
    const float4* gp = (const float4*)gpart;
    float4 q0 = gp[((size_t)0  + m) * 512 + j];
    float4 q1 = gp[((size_t)32 + m) * 512 + j];
    float4 q2 = gp[((size_t)64 + m) * 512 + j];
    float4 q3 = gp[((size_t)96 + m) * 512 + j];
    float gi = (q0.x + q1.x) + (q2.x + q3.x);
    float gf = (q0.y + q1.y) + (q2.y + q3.y);
    float gg = (q0.z + q1.z) + (q2.z + q3.z);
    float go = (q0.w + q1.w) + (q2.w + q3.w);
    size_t ridx = ((size_t)rb * 2 + l) * B_ * H_ + (size_t)m * 512 + j;
    size_t widx = ((size_t)wb * 2 + l) * B_ * H_ + (size_t)m * 512 + j;
    float cold = cbuf[ridx];
    float si = 1.f / (1.f + expf(-gi));
    float sf = 1.f / (1.f + expf(-gf));
    float so = 1.f / (1.f + expf(-go));
    float cn = sf * cold + si * tanhf(gg);
    cbuf[widx] = cn;
    hbuf[widx] = so * tanhf(cn);
}

// q-projection + attention for one (b,h): grid (32,8) x 64 thr (1 wave).
__global__ __launch_bounds__(64) void attn_kernel(
    int t, const float* __restrict__ hbuf,
    const float* __restrict__ Wqt, const float* __restrict__ bq,
    const float* __restrict__ kT, const float* __restrict__ vT,
    float* __restrict__ attnT) {
    const int wb = t & 1;
    const int b = blockIdx.x, h = blockIdx.y;
    const int lane = threadIdx.x;
    const float* hrow = hbuf + ((size_t)wb * 2 + 1) * B_ * H_ + (size_t)b * 512;
    const int n = h * 64 + lane;
    float q = bq[n];
    const float* Wp = Wqt + n;
    float c0 = Wp[(size_t)0 * 512], c1 = Wp[(size_t)1 * 512];
    float c2 = Wp[(size_t)2 * 512], c3 = Wp[(size_t)3 * 512];
    float c4 = Wp[(size_t)4 * 512], c5 = Wp[(size_t)5 * 512];
    float c6 = Wp[(size_t)6 * 512], c7 = Wp[(size_t)7 * 512];
    for (int k = 0; k < 512; k += 8) {
        float t0 = Wp[(size_t)(k +  8) * 512], t1 = Wp[(size_t)(k +  9) * 512];
        float t2 = Wp[(size_t)(k + 10) * 512], t3 = Wp[(size_t)(k + 11) * 512];
        float t4 = Wp[(size_t)(k + 12) * 512], t5 = Wp[(size_t)(k + 13) * 512];
        float t6 = Wp[(size_t)(k + 14) * 512], t7 = Wp[(size_t)(k + 15) * 512];
        q += hrow[k+0]*c0 + hrow[k+1]*c1 + hrow[k+2]*c2 + hrow[k+3]*c3
           + hrow[k+4]*c4 + hrow[k+5]*c5 + hrow[k+6]*c6 + hrow[k+7]*c7;
        c0 = t0; c1 = t1; c2 = t2; c3 = t3; c4 = t4; c5 = t5; c6 = t6; c7 = t7;
    }
    // scores (lane holds s = 2*lane, 2*lane+1)
    const float* kTb = kT + ((size_t)b * NH_ + h) * DK_ * S_;
    float s0 = 0.f, s1 = 0.f;
    for (int d = 0; d < 64; ++d) {
        float qd = __shfl(q, d, 64);
        float2 kk2 = *(const float2*)(kTb + (size_t)d * S_ + 2 * lane);
        s0 += qd * kk2.x;
        s1 += qd * kk2.y;
    }
    s0 *= 0.125f;
    s1 *= 0.125f;
    float mx = fmaxf(s0, s1);
    #pragma unroll
    for (int o = 32; o; o >>= 1) mx = fmaxf(mx, __shfl_xor(mx, o, 64));
    float e0 = expf(s0 - mx), e1 = expf(s1 - mx);
    float sum = e0 + e1;
    #pragma unroll
    for (int o = 32; o; o >>= 1) sum += __shfl_xor(sum, o, 64);
    float inv = 1.f / sum;
    float p0 = e0 * inv, p1 = e1 * inv;
    // attn accumulate (lane = d)
    const float* vTb = vT + ((size_t)b * NH_ + h) * S_ * DK_;
    float a = 0.f;
    for (int s = 0; s < 128; s += 2) {
        float pa = __shfl(p0, s >> 1, 64);
        float pb = __shfl(p1, s >> 1, 64);
        a += pa * vTb[(size_t)s * DK_ + lane] + pb * vTb[(size_t)(s + 1) * DK_ + lane];
    }
    attnT[(size_t)n * 32 + b] = a;  // [512][32] for scalar loads downstream
}

// logits partials vs Weff: grid (125 nblk, 4 kblk) x 256 thr; 32 batch acc/thread.
__global__ __launch_bounds__(256) void logits_kernel(
    const float* __restrict__ WeffT, const float* __restrict__ attnT,
    float* __restrict__ part) {
    const int n = blockIdx.x * 256 + threadIdx.x;
    const int kb = blockIdx.y;
    const int k0 = kb * 128;
    float acc[32];
    #pragma unroll
    for (int m = 0; m < 32; ++m) acc[m] = 0.f;
    const float* Wp = WeffT + (size_t)k0 * V_ + n;
    float c0 = Wp[0], c1 = Wp[(size_t)1 * V_];
    float d0 = Wp[(size_t)2 * V_], d1 = Wp[(size_t)3 * V_];
    for (int kk = 0; kk < 128; kk += 2) {
        float e0 = Wp[(size_t)(kk + 4) * V_];  // last iters over-read <=512KB -> Wcat, discarded
        float e1 = Wp[(size_t)(kk + 5) * V_];
        const float* ar = attnT + (size_t)(k0 + kk) * 32;  // uniform -> s_load
        #pragma unroll
        for (int m = 0; m < 32; ++m) acc[m] += ar[m] * c0 + ar[32 + m] * c1;
        c0 = d0; c1 = d1; d0 = e0; d1 = e1;
    }
    float* pp = part + (size_t)kb * 32 * V_ + n;
    #pragma unroll
    for (int m = 0; m < 32; ++m) pp[(size_t)m * V_] = acc[m];
}

// finalize: sum 4 partials + beff, write out[:,t,:], per-block argmax keys.
__global__ __launch_bounds__(256) void final_kernel(
    int t, const float* __restrict__ part, const float* __restrict__ beff,
    float* __restrict__ out, unsigned long long* __restrict__ bkeys) {
    int n = blockIdx.x * 256 + threadIdx.x;
    float bias = beff[n];
    __shared__ unsigned long long red[4][32];
    const float* p0 = part + n;
    const float* p1 = part + (size_t)32 * V_ + n;
    const float* p2 = part + (size_t)64 * V_ + n;
    const float* p3 = part + (size_t)96 * V_ + n;
    for (int m = 0; m < 32; ++m) {
        float v = ((p0[(size_t)m * V_] + p1[(size_t)m * V_]) +
                   (p2[(size_t)m * V_] + p3[(size_t)m * V_])) + bias;
        out[((size_t)m * 128 + t) * V_ + n] = v;
        unsigned u = __float_as_uint(v);
        u = (u & 0x80000000u) ? ~u : (u | 0x80000000u);
        unsigned long long key =
            ((unsigned long long)u << 32) | (unsigned long long)(0xFFFFFFFFu - (unsigned)n);
        #pragma unroll
        for (int o = 32; o; o >>= 1) {
            unsigned long long other = __shfl_xor(key, o, 64);
            key = other > key ? other : key;
        }
        if ((threadIdx.x & 63) == 0) red[threadIdx.x >> 6][m] = key;
    }
    __syncthreads();
    if (threadIdx.x < 32) {
        int m = threadIdx.x;
        unsigned long long k0 = red[0][m], k1 = red[1][m];
        unsigned long long k2 = red[2][m], k3 = red[3][m];
        unsigned long long kk = k0 > k1 ? k0 : k1;
        unsigned long long k23 = k2 > k3 ? k2 : k3;
        kk = kk > k23 ? kk : k23;
        bkeys[blockIdx.x * 32 + m] = kk;
    }
}

// ---------------- launcher ----------------

extern "C" void kernel_launch(void* const* d_in, const int* in_sizes, int n_in,
                              void* d_out, int out_size, void* d_ws, size_t ws_size,
                              hipStream_t stream) {
    const float* hs     = (const float*)d_in[0];
    const float* hidden = (const float*)d_in[1];
    const float* cell   = (const float*)d_in[2];
    const float* emb    = (const float*)d_in[3];
    const float* W_ih   = (const float*)d_in[4];
    const float* W_hh   = (const float*)d_in[5];
    const float* b_ih   = (const float*)d_in[6];
    const float* b_hh   = (const float*)d_in[7];
    const float* Wq     = (const float*)d_in[8];
    const float* bq     = (const float*)d_in[9];
    const float* Wk     = (const float*)d_in[10];
    const float* bk     = (const float*)d_in[11];
    const float* Wv     = (const float*)d_in[12];
    const float* bv     = (const float*)d_in[13];
    const float* Wo     = (const float*)d_in[14];
    const float* bo     = (const float*)d_in[15];
    const float* W_out  = (const float*)d_in[16];
    const float* b_out  = (const float*)d_in[17];
    float* out = (float*)d_out;
    float* ws = (float*)d_ws;

    float* WeffT = ws + o_WeffT;
    float* Wcat  = ws + o_Wcat;
    float* Wqt   = ws + o_Wqt;
    float* WkvT  = ws + o_WkvT;
    float* kT    = ws + o_kT;
    float* vT    = ws + o_vT;
    float* hbuf  = ws + o_h;
    float* cbuf  = ws + o_c;
    float* attnT = ws + o_attnT;
    float* gpart = ws + o_gpart;
    float* partb = ws + o_part;
    float* beff  = ws + o_beff;
    unsigned long long* bkeys = (unsigned long long*)(ws + o_keys);

    // init recurrent state (pp=0 holds both layers contiguously, same layout as inputs)
    hipMemcpyAsync(hbuf, hidden, (size_t)2 * B_ * H_ * sizeof(float),
                   hipMemcpyDeviceToDevice, stream);
    hipMemcpyAsync(cbuf, cell, (size_t)2 * B_ * H_ * sizeof(float),
                   hipMemcpyDeviceToDevice, stream);

    zero_kernel<<<500, 256, 0, stream>>>(out);
    transpose_k<<<dim3(16, 16), 256, 0, stream>>>(Wq, Wqt, 512, 512, 512);
    transpose_k<<<dim3(16, 16), 256, 0, stream>>>(Wk, WkvT, 512, 512, 1024);
    transpose_k<<<dim3(16, 16), 256, 0, stream>>>(Wv, WkvT + 512, 512, 512, 1024);
    lstm_prep<<<dim3(16, 32, 2), 256, 0, stream>>>(W_ih, W_hh, Wcat);
    kv_kernel<<<dim3(4, 128), 256, 0, stream>>>(hs, WkvT, bk, bv, kT, vT);
    weff_kernel<<<dim3(125, 16), 256, 0, stream>>>(W_out, Wo, bo, b_out, WeffT, beff);

    for (int t = 1; t < 128; ++t) {
        gates_kernel<<<dim3(8, 8, 4), 256, 0, stream>>>(0, t, emb, Wcat, b_ih, b_hh,
                                                        bkeys, hbuf, gpart);
        act_kernel<<<64, 256, 0, stream>>>(0, t, gpart, hbuf, cbuf);
        gates_kernel<<<dim3(8, 8, 4), 256, 0, stream>>>(1, t, emb, Wcat, b_ih, b_hh,
                                                        bkeys, hbuf, gpart);
        act_kernel<<<64, 256, 0, stream>>>(1, t, gpart, hbuf, cbuf);
        attn_kernel<<<dim3(32, 8), 64, 0, stream>>>(t, hbuf, Wqt, bq, kT, vT, attnT);
        logits_kernel<<<dim3(125, 4), 256, 0, stream>>>(WeffT, attnT, partb);
        final_kernel<<<125, 256, 0, stream>>>(t, partb, beff, out, bkeys);
    }
}